// Round 15
// baseline (240.026 us; speedup 1.0000x reference)
//
#include <hip/hip_runtime.h>
#include <hip/hip_bf16.h>
#include <math.h>

#define N_NODES 50000
#define N_EDGES 800000
#define IN_DIM  128
#define MEM_DIM 32
#define OUT_DIM 64
#define NB_SCAN ((N_NODES + 255) / 256)   // 196
#define SCALE   0.17677669529663687f      // 1/sqrt(32)
#define LOG2E   1.44269504088896f
#define LDS_AROW 168                      // padded A-tile row stride (elems)
#define NGB 3125                          // single-tile GEMM blocks (16 nodes each)
#define NPREP 200                         // prep blocks (200*256 == 51200)

typedef __attribute__((ext_vector_type(8))) short bf16x8;
typedef __attribute__((ext_vector_type(4))) float f32x4;

__device__ __forceinline__ short f2bf(float f) {
    union { float f; unsigned u; } v; v.f = f;
    unsigned r = v.u + 0x7FFF + ((v.u >> 16) & 1);   // round-to-nearest-even
    return (short)(r >> 16);
}
__device__ __forceinline__ float lo16(unsigned u) { return __uint_as_float(u << 16); }
__device__ __forceinline__ float hi16(unsigned u) { return __uint_as_float(u & 0xffff0000u); }

// Cross-lane add via DPP (VALU pipe, not LDS). CTRL: 0xB1=quad_perm xor1,
// 0x4E=quad_perm xor2, 0x124=row_ror:4, 0x128=row_ror:8.
template <int CTRL>
__device__ __forceinline__ float dpp_mov(float x) {
    return __int_as_float(__builtin_amdgcn_update_dpp(
        0, __float_as_int(x), CTRL, 0xF, 0xF, true));
}
// xor16 within each 32-lane half (BitMode: xor=16, and=0x1F)
__device__ __forceinline__ float swz16(float x) {
    return __int_as_float(__builtin_amdgcn_ds_swizzle(__float_as_int(x), 0x401F));
}
// sum over the lane's 32-lane half: 4 DPP adds + 1 swizzle. Each 32-lane
// half reduces INDEPENDENTLY (one pass serves 2 records).
__device__ __forceinline__ float half_reduce(float pr) {
    pr += dpp_mov<0xB1>(pr);
    pr += dpp_mov<0x4E>(pr);
    pr += dpp_mov<0x124>(pr);
    pr += dpp_mov<0x128>(pr);
    pr += swz16(pr);
    return pr;
}

// ---------------------------------------------------------------------------
// prep_hist_k: r12-VERIFIED fusion, verbatim. Blocks [0,NPREP): bf16 weight
// bank in lane-coalesced B-frag layout. Blocks [NPREP,NPREP+3125): 8-replica
// dst histogram + rank capture (cntr pre-zeroed by hipMemsetAsync).
// ---------------------------------------------------------------------------
__global__ __launch_bounds__(256) void prep_hist_k(
    const float* __restrict__ Wq, const float* __restrict__ Wk,
    const float* __restrict__ Wv, const float* __restrict__ Wskip,
    const float* __restrict__ We_k, unsigned short* __restrict__ wtb,
    const int* __restrict__ dst, int* __restrict__ cntr, int* __restrict__ rank)
{
    if (blockIdx.x >= NPREP) {
        const int e = (blockIdx.x - NPREP) * 256 + threadIdx.x;   // 3125*256 == E
        rank[e] = atomicAdd(&cntr[((e >> 8) & 7) * N_NODES + dst[e]], 1);
        return;
    }
    const int i = blockIdx.x * 256 + threadIdx.x;   // < 51200 == 5*64*160
    const int m = i / 10240, rem = i % 10240, c = rem / 160, k = rem % 160;
    float v;
    if (m == 4) {
        const int h = c >> 5, kk = c & 31;
        v = 0.f;
        #pragma unroll
        for (int j = 0; j < 32; ++j)
            v += Wq[k * 64 + h * 32 + j] * We_k[kk * 64 + h * 32 + j];
        v *= SCALE;
    } else {
        const float* W = (m == 0) ? Wq : (m == 1) ? Wk : (m == 2) ? Wv : Wskip;
        v = W[k * 64 + c];
        if (m == 0) v *= SCALE;
    }
    const int g = c >> 4, l15 = c & 15;
    const int kb = k >> 5, quad = (k >> 3) & 3, j = k & 7;
    wtb[(size_t)((((m * 5 + kb) * 4 + g) * 64) + quad * 16 + l15) * 8 + j] =
        (unsigned short)f2bf(v);
}

// ---------------------------------------------------------------------------
// gemm_scan_k: blocks [0,NGB) = r13-verified single-tile node GEMM (B-frags
// in registers, LDS A-tile, by-dim zkv layout, contiguous-line epilogue).
// Blocks [NGB,NGB+196) = the r12/r13-twice-verified flag-based scan1+scan2,
// adapted to 320 threads (data work guarded tid<256; barriers uniform).
// The 5us scan hides entirely under the GEMM arm.
// ---------------------------------------------------------------------------
__global__ __launch_bounds__(320) void gemm_scan_k(
    const float* __restrict__ x, const float* __restrict__ mem,
    const unsigned short* __restrict__ wtb,
    unsigned short* __restrict__ qq, unsigned short* __restrict__ zkv,
    float* __restrict__ out,
    int* __restrict__ cntr, int* __restrict__ base, int* __restrict__ bsum,
    int* __restrict__ deg, int* __restrict__ flag)
{
    const int tid = threadIdx.x;
    __shared__ unsigned short sA[16 * LDS_AROW];    // 5.25 KB (gemm arm)
    __shared__ unsigned short sQQ[16 * 128];        // 4 KB
    __shared__ unsigned short sKV[16 * 128];        // 4 KB
    __shared__ float          sOUT[16 * 64];        // 4 KB
    __shared__ int            sh[256];              // scan arm
    __shared__ int            isLast;

    if (blockIdx.x >= NGB) {
        // ---- scan arm (r12-verified logic; 320-thread adaptation) ----
        const int sb = blockIdx.x - NGB;            // 0..195
        const int i  = sb * 256 + tid;              // valid only for tid<256
        int tot = 0;
        if (tid < 256 && i < N_NODES) {
            int off = 0;
            #pragma unroll
            for (int r = 0; r < 8; ++r) {
                const int c = cntr[r * N_NODES + i];
                cntr[r * N_NODES + i] = off;
                off += c;
            }
            tot = off;
            deg[i] = tot;
        }
        if (tid < 256) sh[tid] = tot;
        __syncthreads();
        int val = tot;
        for (int off = 1; off < 256; off <<= 1) {
            const int y = (tid < 256 && tid >= off) ? sh[tid - off] : 0;
            __syncthreads();
            if (tid < 256) { val += y; sh[tid] = val; }
            __syncthreads();
        }
        if (tid < 256 && i < N_NODES) base[i] = val - tot;
        if (tid == 255) {
            bsum[sb] = val;
            __threadfence();                         // publish bsum write
            isLast = (atomicAdd(flag, 1) == NB_SCAN - 1);
        }
        __syncthreads();
        if (!isLast) return;

        // last-arriving scan block: fold scan2 (196-element exclusive scan)
        __threadfence();                             // acquire
        volatile int* vb = bsum;
        const int v = (tid < NB_SCAN) ? vb[tid] : 0;
        if (tid < 256) sh[tid] = v;
        __syncthreads();
        int val2 = v;
        for (int off = 1; off < 256; off <<= 1) {
            const int y = (tid < 256 && tid >= off) ? sh[tid - off] : 0;
            __syncthreads();
            if (tid < 256) { val2 += y; sh[tid] = val2; }
            __syncthreads();
        }
        if (tid < NB_SCAN) bsum[tid] = val2 - v;
        return;
    }

    // ---- gemm arm (r13-verified body verbatim) ----
    const int w    = tid >> 6;                  // 0..4 (matrix id)
    const int lane = tid & 63;
    const int l15  = lane & 15;
    const int quad = lane >> 4;
    const int nb   = blockIdx.x * 16;

    // B-frags: coalesced 1KB loads, L2-resident wtb
    bf16x8 bfrag[5][4];
    #pragma unroll
    for (int kb = 0; kb < 5; ++kb)
        #pragma unroll
        for (int g = 0; g < 4; ++g)
            bfrag[kb][g] = *(const bf16x8*)(wtb +
                (size_t)(((w * 5 + kb) * 4 + g) * 64 + lane) * 8);

    // cooperative coalesced stage: x (16x128) + mem (16x32) -> sA
    for (int i = tid; i < 640; i += 320) {
        float4 f;
        int row, dim;
        if (i < 512) {                       // x part: 16 rows x 32 float4
            row = i >> 5; dim = (i & 31) * 4;
            f = *(const float4*)(x + (size_t)(nb + row) * IN_DIM + dim);
        } else {                             // mem part: 16 rows x 8 float4
            const int j = i - 512;
            row = j >> 3; dim = 128 + (j & 7) * 4;
            f = *(const float4*)(mem + (size_t)(nb + row) * MEM_DIM + (dim - 128));
        }
        unsigned short* d2 = sA + row * LDS_AROW + dim;
        d2[0] = (unsigned short)f2bf(f.x); d2[1] = (unsigned short)f2bf(f.y);
        d2[2] = (unsigned short)f2bf(f.z); d2[3] = (unsigned short)f2bf(f.w);
    }
    __syncthreads();

    f32x4 acc[4];
    #pragma unroll
    for (int g = 0; g < 4; ++g) acc[g] = (f32x4)0.0f;
    #pragma unroll
    for (int kb = 0; kb < 5; ++kb) {
        const bf16x8 afrag =
            *(const bf16x8*)(sA + l15 * LDS_AROW + kb * 32 + quad * 8);
        #pragma unroll
        for (int g = 0; g < 4; ++g)
            acc[g] = __builtin_amdgcn_mfma_f32_16x16x32_bf16(
                         afrag, bfrag[kb][g], acc[g], 0, 0, 0);
    }

    // stage results into LDS out-tiles
    #pragma unroll
    for (int g = 0; g < 4; ++g) {
        #pragma unroll
        for (int r = 0; r < 4; ++r) {
            const int row = quad * 4 + r;
            const int col = 16 * g + l15;
            if (w == 3)
                sOUT[row * 64 + col] = acc[g][r];
            else if (w == 0)
                sQQ[row * 128 + 2 * col] = (unsigned short)f2bf(acc[g][r]);
            else if (w == 4)
                sQQ[row * 128 + 2 * col + 1] = (unsigned short)f2bf(acc[g][r]);
            else   // by-dim layout: d*4 + h + 2*isV  (d=col&31, h=col>>5)
                sKV[row * 128 + (col & 31) * 4 + (col >> 5) + 2 * (w == 2)] =
                    (unsigned short)f2bf(acc[g][r]);
        }
    }
    __syncthreads();

    // contiguous full-line epilogue: 3 x 4KB block copies
    if (tid < 256) {
        ((uint4*)(qq + (size_t)nb * 128))[tid]       = ((const uint4*)sQQ)[tid];
        ((uint4*)(zkv + (size_t)nb * 128))[tid]      = ((const uint4*)sKV)[tid];
        ((float4*)(out + (size_t)nb * OUT_DIM))[tid] = ((const float4*)sOUT)[tid];
    }
}

// ---------------------------------------------------------------------------
// scatter_k: ATOMIC-FREE 8B scatter, standalone (r8/r13-verified verbatim).
//   pos = base[d] + bsum[d>>8] + cntr[r][d] + rank[e],  r = (e>>8)&7.
// ---------------------------------------------------------------------------
__global__ __launch_bounds__(256) void scatter_k(
    const int* __restrict__ srcA, const int* __restrict__ dstA,
    const float* __restrict__ tA, const int* __restrict__ rank,
    const int* __restrict__ base, const int* __restrict__ bsum,
    const int* __restrict__ cntr, float2* __restrict__ edata2)
{
    const int e = blockIdx.x * 256 + threadIdx.x;   // 3125*256 == E
    const int d = dstA[e];
    const int pos = base[d] + bsum[d >> 8]
                  + cntr[((e >> 8) & 7) * N_NODES + d] + rank[e];
    float2 rc;
    rc.x = __int_as_float(srcA[e]);
    rc.y = tA[e];
    edata2[pos] = rc;
}

// ---------------------------------------------------------------------------
// agg_k: r9/r11/r13-verified body VERBATIM. One wave per node, two records
// per iteration via the by-dim zkv layout; DPP half_reduce serves both
// records in one pass per head.
// ---------------------------------------------------------------------------
__global__ __launch_bounds__(256) void agg_k(
    const float2* __restrict__ edata2, const int* __restrict__ base,
    const int* __restrict__ bsum, const int* __restrict__ degA,
    const float* __restrict__ w_time, const float* __restrict__ b_time,
    const unsigned short* __restrict__ qq,
    const unsigned short* __restrict__ zkv,
    const float* __restrict__ We_v, float* __restrict__ out)
{
    __shared__ float recs[4][64];               // epilogue strips only
    const int tid  = threadIdx.x;
    const int w    = tid >> 6;
    const int lane = tid & 63;
    const int h    = lane >> 5;                 // which record of the pair
    const int l31  = lane & 31;                 // dim
    const int n    = blockIdx.x * 4 + w;

    const int b0  = base[n] + bsum[n >> 8];
    const int deg = degA[n];

    const float wt = w_time[l31];
    const float bt = b_time[l31];

    // dst-side q/qek for BOTH heads at this dim, once; fold log2e.
    const unsigned qv0 = *(const unsigned*)(qq + (size_t)n * 128 + 2 * l31);
    const unsigned qv1 = *(const unsigned*)(qq + (size_t)n * 128 + 64 + 2 * l31);
    const float q0  = lo16(qv0) * LOG2E, qe0 = hi16(qv0) * LOG2E;
    const float q1  = lo16(qv1) * LOG2E, qe1 = hi16(qv1) * LOG2E;

    float av0 = 0.f, av1 = 0.f, pte0 = 0.f, pte1 = 0.f, lp0 = 0.f, lp1 = 0.f;

    #define PAIR_COMPUTE(RR, KV, MASKED)                                     \
    {                                                                        \
        const float te = __cosf((RR).y * wt + bt);                           \
        float p0 = q0 * lo16((KV).x) + qe0 * te;                             \
        float p1 = q1 * hi16((KV).x) + qe1 * te;                             \
        p0 = half_reduce(p0);                                                \
        p1 = half_reduce(p1);                                                \
        float pe0 = exp2f(p0), pe1 = exp2f(p1);                              \
        if (MASKED) { if (h) { pe0 = 0.f; pe1 = 0.f; } }                     \
        av0  += pe0 * lo16((KV).y);                                          \
        av1  += pe1 * hi16((KV).y);                                          \
        pte0 += pe0 * te;                                                    \
        pte1 += pe1 * te;                                                    \
        lp0  += pe0;                                                         \
        lp1  += pe1;                                                         \
    }

    const int fp = deg >> 1;                    // full pairs
    int p = 0;
    for (; p + 4 <= fp; p += 4) {               // 4 pairs = 8 records batched
        float2 r[4];
        #pragma unroll
        for (int j = 0; j < 4; ++j) r[j] = edata2[b0 + 2 * (p + j) + h];
        uint2 kv[4];
        #pragma unroll
        for (int j = 0; j < 4; ++j)
            kv[j] = *(const uint2*)((const char*)zkv +
                      (((unsigned)__float_as_int(r[j].x)) << 8) + (l31 << 3));
        #pragma unroll
        for (int j = 0; j < 4; ++j) PAIR_COMPUTE(r[j], kv[j], false)
    }
    for (; p < fp; ++p) {                       // leftover full pairs
        const float2 r = edata2[b0 + 2 * p + h];
        const uint2 kv = *(const uint2*)((const char*)zkv +
                      (((unsigned)__float_as_int(r.x)) << 8) + (l31 << 3));
        PAIR_COMPUTE(r, kv, false)
    }
    if (deg & 1) {                              // odd last record: lower half only
        const float2 r = edata2[b0 + deg - 1];
        const uint2 kv = *(const uint2*)((const char*)zkv +
                      (((unsigned)__float_as_int(r.x)) << 8) + (l31 << 3));
        PAIR_COMPUTE(r, kv, true)
    }
    #undef PAIR_COMPUTE

    // ---- merge halves (even-record sums + odd-record sums) ----
    av0  += __shfl_xor(av0, 32);
    av1  += __shfl_xor(av1, 32);
    pte0 += __shfl_xor(pte0, 32);
    pte1 += __shfl_xor(pte1, 32);
    lp0  += __shfl_xor(lp0, 32);
    lp1  += __shfl_xor(lp1, 32);

    // ---- fused We_v epilogue (rec[h*32+d] = pte[h][d]) ----
    float* rec = &recs[w][0];
    rec[lane] = h ? pte1 : pte0;
    float wev[32];
    #pragma unroll
    for (int k = 0; k < 32; ++k) wev[k] = We_v[k * 64 + lane];

    const float lp  = h ? lp1 : lp0;
    const float av  = h ? av1 : av0;
    const float inv = (lp > 0.f) ? 1.f / lp : 0.f;
    const float4* pv = (const float4*)(rec + h * 32);
    float dot = 0.f;
    #pragma unroll
    for (int k = 0; k < 8; ++k) {
        const float4 c = pv[k];
        dot += c.x * wev[4 * k]     + c.y * wev[4 * k + 1]
             + c.z * wev[4 * k + 2] + c.w * wev[4 * k + 3];
    }

    out[(size_t)n * OUT_DIM + lane] += (av + dot) * inv;   // skip already there
}

extern "C" void kernel_launch(void* const* d_in, const int* in_sizes, int n_in,
                              void* d_out, int out_size, void* d_ws, size_t ws_size,
                              hipStream_t stream) {
    (void)in_sizes; (void)n_in; (void)out_size; (void)ws_size;
    const int*   src    = (const int*)d_in[0];
    const int*   dst    = (const int*)d_in[1];
    const float* t      = (const float*)d_in[2];
    const float* x      = (const float*)d_in[3];
    const float* mem    = (const float*)d_in[4];
    const float* w_time = (const float*)d_in[5];
    const float* b_time = (const float*)d_in[6];
    const float* Wq     = (const float*)d_in[7];
    const float* Wk     = (const float*)d_in[8];
    const float* Wv     = (const float*)d_in[9];
    const float* We_k   = (const float*)d_in[10];
    const float* We_v   = (const float*)d_in[11];
    const float* Wskip  = (const float*)d_in[12];

    // workspace layout (16B-aligned chunks)
    char* p = (char*)d_ws;
    unsigned short* zkv = (unsigned short*)p; p += (size_t)N_NODES * 128 * 2; // 12.8 MB (by-dim k/v)
    unsigned short* qq  = (unsigned short*)p; p += (size_t)N_NODES * 128 * 2; // 12.8 MB (q|qek interleaved)
    unsigned short* wtb = (unsigned short*)p; p += (size_t)5 * 64 * 160 * 2;  // 100 KB
    float2* edata2 = (float2*)p; p += (size_t)N_EDGES * 8;                    // 6.4 MB
    int*  cntr  = (int*)p;   p += (size_t)8 * N_NODES * 4;   // zeroed by memset
    int*  flag  = (int*)p;   p += 16;                        // scan arm counter
    int*  rank  = (int*)p;   p += (size_t)N_EDGES * 4;       // 3.2 MB
    int*  base  = (int*)p;   p += (size_t)N_NODES * 4;
    int*  deg   = (int*)p;   p += (size_t)N_NODES * 4;
    int*  bsum  = (int*)p;   p += 256 * 4;
    float* out  = (float*)d_out;

    hipMemsetAsync(cntr, 0, (size_t)8 * N_NODES * 4 + 16, stream);  // cntr+flag
    prep_hist_k<<<NPREP + 3125, 256, 0, stream>>>(Wq, Wk, Wv, Wskip, We_k, wtb,
                                                  dst, cntr, rank);
    gemm_scan_k<<<NGB + NB_SCAN, 320, 0, stream>>>(x, mem, wtb, qq, zkv, out,
                                                   cntr, base, bsum, deg, flag);
    scatter_k<<<N_EDGES / 256, 256, 0, stream>>>(src, dst, t, rank, base, bsum,
                                                 cntr, edata2);
    agg_k    <<<N_NODES / 4, 256, 0, stream>>>(edata2, base, bsum, deg,
                                               w_time, b_time, qq, zkv, We_v, out);
}